// Round 16
// baseline (120.199 us; speedup 1.0000x reference)
//
#include <hip/hip_runtime.h>
#include <hip/hip_bf16.h>

typedef unsigned short u16;
typedef unsigned int   u32;
typedef __attribute__((ext_vector_type(8))) short bf16x8;
typedef __attribute__((ext_vector_type(4))) float f32x4;

#define SCALE 0.08838834764831845f                 // 1/sqrt(2*64)
#define SCLOG 0.12752040542575836f                 // SCALE * log2(e)

__device__ inline u16 f2bf(float f) {
  u32 u = __builtin_bit_cast(u32, f);
  u = (u + 0x7FFFu + ((u >> 16) & 1u)) >> 16;      // RNE
  return (u16)u;
}
__device__ inline float bf2f(u16 b) {
  u32 u = (u32)b << 16;
  return __builtin_bit_cast(float, u);
}
// HW bf16 cvt (compiler emits the HW cvt; scalar-cast path per m240)
__device__ __forceinline__ u16 cvbf(float f) {
  return __builtin_bit_cast(u16, __float2bfloat16(f));
}
__device__ __forceinline__ u32 pkbf(float a, float b) {   // low=a, high=b
  return (u32)cvbf(a) | ((u32)cvbf(b) << 16);
}
// raw v_exp_f32 (exp2): OCML exp2f is ~17 instr without fast-math
__device__ __forceinline__ float fexp2(float x) {
#if __has_builtin(__builtin_amdgcn_exp2f)
  return __builtin_amdgcn_exp2f(x);
#else
  float r; asm("v_exp_f32 %0, %1" : "=v"(r) : "v"(x)); return r;
#endif
}

// async global->LDS, 16B per lane; LDS dest is wave-uniform base + lane*16.
__device__ __forceinline__ void glds16(const u16* g, u16* l) {
  __builtin_amdgcn_global_load_lds(
      (__attribute__((address_space(1))) void*)g,
      (__attribute__((address_space(3))) void*)l, 16, 0, 0);
}

// ---------------------------------------------------------------------------
// fp32 -> bf16 bulk convert (x and x_knowledge). grid (1024, 2), 8 elems/thr.
// ---------------------------------------------------------------------------
__global__ __launch_bounds__(256) void cvt_bf16(const float* __restrict__ a,
                                                const float* __restrict__ b,
                                                u16* __restrict__ oa,
                                                u16* __restrict__ ob) {
  const float* in = blockIdx.y ? b : a;
  u16* out = blockIdx.y ? ob : oa;
  const int i = (blockIdx.x * 256 + threadIdx.x) * 8;
  float4 f0 = *(const float4*)(in + i);
  float4 f1 = *(const float4*)(in + i + 4);
  alignas(16) u16 t[8] = {f2bf(f0.x), f2bf(f0.y), f2bf(f0.z), f2bf(f0.w),
                          f2bf(f1.x), f2bf(f1.y), f2bf(f1.z), f2bf(f1.w)};
  *(uint4*)(out + i) = *(const uint4*)t;
}

// ---------------------------------------------------------------------------
// fp32 -> bf16 row-major cast of the 4 first-stage Q/K weights (for wcomb B).
// grid (128, 4), 8 elems/thr.
// ---------------------------------------------------------------------------
struct CPtrs { const float* p[4]; };

__global__ __launch_bounds__(256) void cvtW(CPtrs cp, u16* __restrict__ out) {
  const float* in = cp.p[blockIdx.y];
  u16* o = out + (size_t)blockIdx.y * 262144;
  const int i = (blockIdx.x * 256 + threadIdx.x) * 8;
  float4 f0 = *(const float4*)(in + i);
  float4 f1 = *(const float4*)(in + i + 4);
  alignas(16) u16 t[8] = {f2bf(f0.x), f2bf(f0.y), f2bf(f0.z), f2bf(f0.w),
                          f2bf(f1.x), f2bf(f1.y), f2bf(f1.z), f2bf(f1.w)};
  *(uint4*)(o + i) = *(const uint4*)t;
}

// ---------------------------------------------------------------------------
// Weight transpose Wt[z][n][k] = W[z][k][n] (fp32->bf16); slots 5,7 scaled
// by SCALE*log2e. Bias packed only for slots 0 (bv) and 9 (bo); effective
// biases for the fused projections come from biasEff.
// ---------------------------------------------------------------------------
struct WPtrs { const float* w[10]; const float* b[10]; };

__global__ __launch_bounds__(256) void transposeW(WPtrs p, u16* __restrict__ out,
                                                  float* __restrict__ biasP) {
  __shared__ u16 ts[64][65];
  const int z = blockIdx.z;
  const float sc = (z == 5 || z == 7) ? SCLOG : 1.0f;
  const float* in = p.w[z];
  u16* o = out + (size_t)z * 262144;
  const int t = threadIdx.x;
  const int k0 = blockIdx.y * 64, n0 = blockIdx.x * 64;
  if (blockIdx.x == 0 && blockIdx.y == 0 && (z == 0 || z == 9)) {
    biasP[z * 512 + t]       = p.b[z][t];
    biasP[z * 512 + t + 256] = p.b[z][t + 256];
  }
  for (int pp = 0; pp < 16; ++pp) {
    int id = t + 256 * pp; int r = id >> 6, c = id & 63;
    ts[r][c] = f2bf(in[(size_t)(k0 + r) * 512 + n0 + c] * sc);
  }
  __syncthreads();
  for (int pp = 0; pp < 16; ++pp) {
    int id = t + 256 * pp; int r = id >> 6, c = id & 63;
    o[(size_t)(n0 + r) * 512 + k0 + c] = ts[c][r];
  }
}

// ---------------------------------------------------------------------------
// Effective bias for fused double-projection: beff[n] = (b1 @ W2 + b2)[n]*sc.
// grid (4), 512 threads; z order q,k,qf,kf -> biasP rows 512..2559.
// ---------------------------------------------------------------------------
struct BEPtrs { const float* b1[4]; const float* w2[4]; const float* b2[4]; };

__global__ __launch_bounds__(512) void biasEff(BEPtrs be, float* __restrict__ biasP) {
  const int z = blockIdx.x, n = threadIdx.x;
  const float sc = (z == 0 || z == 2) ? SCLOG : 1.0f;
  const float* b1 = be.b1[z];
  const float* w2 = be.w2[z];
  float s = 0.0f;
  for (int j = 0; j < 512; ++j) s += b1[j] * w2[j * 512 + n];
  biasP[(1 + z) * 512 + n] = (s + be.b2[z][n]) * sc;
}

// ---------------------------------------------------------------------------
// GEMM: 128x128 tile, BK=64, 4 waves (2x2) of 64x64. Single-buffered 32 KiB
// LDS with global_load_lds width-16 staging. Linear LDS. NB=true skips bias.
// ---------------------------------------------------------------------------
struct GemmBatch {
  const u16* A[4];
  const u16* Ax;
  int xsplit;
  void* out[5];        // indexed by (wrow>>9) - (wrow0>>9)
  int wrow0, zstride;
};

template <typename TOUT, bool NB>
__global__ __launch_bounds__(256, 4) void gemm4(GemmBatch gb,
    const u16* __restrict__ Wt, const float* __restrict__ biasP) {
  const int tx = blockIdx.x, z = blockIdx.z;
  const u16* A = (tx < gb.xsplit) ? gb.A[z] : gb.Ax;
  const int wrow = gb.wrow0 + z * gb.zstride + tx * 128;
  const int m0 = blockIdx.y * 128;
  const u16* B = Wt + (size_t)wrow * 512;
  const float* bias = biasP + wrow;

  const int t = threadIdx.x, wid = t >> 6, lane = t & 63;
  const int lg = lane >> 4, ln = lane & 15;
  const int wr = wid >> 1, wc = wid & 1;

  __shared__ u16 As[128][64];
  __shared__ u16 Bs[128][64];

  const u16* Ag = A + (size_t)m0 * 512;
  const int lrow = lane >> 3, lch = lane & 7;

  f32x4 acc[4][4];
  #pragma unroll
  for (int i = 0; i < 4; ++i)
    #pragma unroll
    for (int j = 0; j < 4; ++j)
      #pragma unroll
      for (int r = 0; r < 4; ++r) acc[i][j][r] = 0.0f;

  for (int kt = 0; kt < 8; ++kt) {
    #pragma unroll
    for (int c = 0; c < 4; ++c) {
      const int row = (wid * 4 + c) * 8 + lrow;
      const size_t go = (size_t)row * 512 + kt * 64 + lch * 8;
      glds16(Ag + go, &As[(wid * 4 + c) * 8][0]);
      glds16(B  + go, &Bs[(wid * 4 + c) * 8][0]);
    }
    __syncthreads();

    #pragma unroll
    for (int ck = 0; ck < 2; ++ck) {
      bf16x8 af[4], bfr[4];
      #pragma unroll
      for (int mi = 0; mi < 4; ++mi)
        af[mi] = *(const bf16x8*)&As[wr * 64 + mi * 16 + ln][ck * 32 + lg * 8];
      #pragma unroll
      for (int ni = 0; ni < 4; ++ni)
        bfr[ni] = *(const bf16x8*)&Bs[wc * 64 + ni * 16 + ln][ck * 32 + lg * 8];
      #pragma unroll
      for (int mi = 0; mi < 4; ++mi)
        #pragma unroll
        for (int ni = 0; ni < 4; ++ni)
          acc[mi][ni] = __builtin_amdgcn_mfma_f32_16x16x32_bf16(
              af[mi], bfr[ni], acc[mi][ni], 0, 0, 0);
    }
    if (kt < 7) __syncthreads();
  }

  TOUT* C = (TOUT*)gb.out[(wrow >> 9) - (gb.wrow0 >> 9)];
  const int nbase = wrow & 511;
  #pragma unroll
  for (int ni = 0; ni < 4; ++ni) {
    const int colw = wc * 64 + ni * 16 + ln;
    const float bv = NB ? 0.0f : bias[colw];
    const int col = nbase + colw;
    #pragma unroll
    for (int mi = 0; mi < 4; ++mi)
      #pragma unroll
      for (int r = 0; r < 4; ++r) {
        const int row = m0 + wr * 64 + mi * 16 + 4 * lg + r;
        const float val = acc[mi][ni][r] + bv;
        if constexpr (sizeof(TOUT) == 4) C[(size_t)row * 512 + col] = val;
        else                             C[(size_t)row * 512 + col] = f2bf(val);
      }
  }
}

// ---------------------------------------------------------------------------
// Per-head V transpose: v1 (2048,64) -> vt (64,2048) per head-block.
// grid (32,16).
// ---------------------------------------------------------------------------
__global__ __launch_bounds__(256) void transposeV(const u16* __restrict__ v1,
                                                  u16* __restrict__ vt) {
  __shared__ u16 ts[64][65];
  const size_t base = (size_t)blockIdx.y * 131072;
  const u16* in = v1 + base;
  u16* out = vt + base;
  const int l0 = blockIdx.x * 64;
  const int t = threadIdx.x;
  const int r = t >> 3, c8 = (t & 7) * 8;
  for (int pp = 0; pp < 2; ++pp) {
    int rr = r + pp * 32;
    *(uint4*)&ts[rr][c8] = *(const uint4*)&in[(size_t)(l0 + rr) * 64 + c8];
  }
  __syncthreads();
  for (int pp = 0; pp < 2; ++pp) {
    int d = r + pp * 32;
    alignas(16) u16 tmp[8];
    #pragma unroll
    for (int i = 0; i < 8; ++i) tmp[i] = ts[c8 + i][d];
    *(uint4*)&out[(size_t)d * 2048 + l0 + c8] = *(const uint4*)tmp;
  }
}

// ---------------------------------------------------------------------------
// Flash attention v8: swapped-operand S^T = mfma(K, Q) with permuted K-rows
// -> in-register P; lane-local defer-max; 8 waves x 32 q; KVBLK=64;
// KV-split x2; dbuf 48 KiB; grid 256 = 1 block/CU. fexp2 (raw v_exp_f32)
// and HW bf16 cvt. Q pre-scaled by SCALE*log2e (log2 domain).
// ---------------------------------------------------------------------------
__global__ __launch_bounds__(512) void attn8(
    const u16* __restrict__ q2, const u16* __restrict__ k2,
    const u16* __restrict__ qf2, const u16* __restrict__ kf2,
    const u16* __restrict__ vtg, u16* __restrict__ opart,
    float2* __restrict__ mlbuf) {
  const int id = blockIdx.x;
  const int nid = (id & 7) * 32 + (id >> 3);   // XCD-bijective
  const int split = nid & 1;
  const int qt = (nid >> 1) & 7;
  const int bh = nid >> 4;
  const size_t base = (size_t)bh * 131072;
  const int kv0 = split * 1024;

  const u16* Q  = q2  + base;
  const u16* Qf = qf2 + base;
  u16* Op = opart + (size_t)split * 2097152 + base;

  const int t = threadIdx.x, wid = t >> 6, lane = t & 63;
  const int lg = lane >> 4, ln = lane & 15;
  const int r0 = qt * 256 + wid * 32;          // this wave's 32 Q rows (local)

  __shared__ u16 K_s [2][64][64];
  __shared__ u16 Kf_s[2][64][64];
  __shared__ u16 Vt_s[2][64][64];

  const int srow = t >> 3, sch = t & 7;        // 64 rows x 8 chunks
  const int fsr = (srow & 3) | (((srow >> 3) & 1) << 2);
  const int sw = (sch ^ fsr) * 8;
  const u16* Ksrc  = k2  + base + (size_t)(kv0 + srow) * 64 + sch * 8;
  const u16* Kfsrc = kf2 + base + (size_t)(kv0 + srow) * 64 + sch * 8;
  const u16* Vsrc  = vtg + base + (size_t)srow * 2048 + kv0 + sch * 8;

  // Q fragments (B-operand: lane ln holds Q row r0+qb*16+ln, chunk lg)
  bf16x8 aq[2][4];
  #pragma unroll
  for (int qb = 0; qb < 2; ++qb) {
    const int row = r0 + qb * 16 + ln;
    aq[qb][0] = *(const bf16x8*)&Q [row * 64 +      lg * 8];
    aq[qb][1] = *(const bf16x8*)&Q [row * 64 + 32 + lg * 8];
    aq[qb][2] = *(const bf16x8*)&Qf[row * 64 +      lg * 8];
    aq[qb][3] = *(const bf16x8*)&Qf[row * 64 + 32 + lg * 8];
  }

  f32x4 oacc[2][4];
  #pragma unroll
  for (int qb = 0; qb < 2; ++qb)
    #pragma unroll
    for (int df = 0; df < 4; ++df)
      #pragma unroll
      for (int r = 0; r < 4; ++r) oacc[qb][df][r] = 0.0f;
  float m_run[2], l_par[2];
  #pragma unroll
  for (int qb = 0; qb < 2; ++qb) { m_run[qb] = -1e30f; l_par[qb] = 0.0f; }

  // A-operand K-row permutation: kv(m,r,lg) = 32*(m>>1)+8*lg+4*(m&1)+r
  const int rbase = 8 * (ln >> 2) + (ln & 3);

  // prologue: stage tile 0
  uint4 rk = *(const uint4*)(Ksrc);
  uint4 rf = *(const uint4*)(Kfsrc);
  uint4 rv = *(const uint4*)(Vsrc);
  *(uint4*)&K_s [0][srow][sw] = rk;
  *(uint4*)&Kf_s[0][srow][sw] = rf;
  *(uint4*)&Vt_s[0][srow][sw] = rv;
  __syncthreads();

  int cur = 0;
  for (int kt = 0; kt < 16; ++kt) {
    if (kt < 15) {                             // issue next-tile loads early
      const int ko = (kt + 1) * 4096;
      rk = *(const uint4*)(Ksrc  + ko);
      rf = *(const uint4*)(Kfsrc + ko);
      rv = *(const uint4*)(Vsrc  + (kt + 1) * 64);
    }

    // ---- S^T = K Q^T + Kf Qf^T : s[qb][m][r] = S[q=r0+16qb+ln][kv(m,r,lg)]
    f32x4 s[2][4];
    #pragma unroll
    for (int m = 0; m < 4; ++m) {
      const int rowg = rbase + 4 * (m & 1) + 32 * (m >> 1);
      const int fz = (rowg & 3) | (((rowg >> 3) & 1) << 2);
      bf16x8 a0 = *(const bf16x8*)&K_s [cur][rowg][((0 + lg) ^ fz) * 8];
      bf16x8 a1 = *(const bf16x8*)&K_s [cur][rowg][((4 + lg) ^ fz) * 8];
      bf16x8 a2 = *(const bf16x8*)&Kf_s[cur][rowg][((0 + lg) ^ fz) * 8];
      bf16x8 a3 = *(const bf16x8*)&Kf_s[cur][rowg][((4 + lg) ^ fz) * 8];
      #pragma unroll
      for (int qb = 0; qb < 2; ++qb) {
        f32x4 a;
        #pragma unroll
        for (int r = 0; r < 4; ++r) a[r] = 0.0f;
        a = __builtin_amdgcn_mfma_f32_16x16x32_bf16(a0, aq[qb][0], a, 0, 0, 0);
        a = __builtin_amdgcn_mfma_f32_16x16x32_bf16(a1, aq[qb][1], a, 0, 0, 0);
        a = __builtin_amdgcn_mfma_f32_16x16x32_bf16(a2, aq[qb][2], a, 0, 0, 0);
        a = __builtin_amdgcn_mfma_f32_16x16x32_bf16(a3, aq[qb][3], a, 0, 0, 0);
        s[qb][m] = a;
      }
    }

    // ---- lane-local defer-max softmax (q = ln + 16*qb per lane) ----
    float smax[2];
    bool viol = false;
    #pragma unroll
    for (int qb = 0; qb < 2; ++qb) {
      float v = fmaxf(fmaxf(s[qb][0][0], s[qb][0][1]),
                      fmaxf(s[qb][0][2], s[qb][0][3]));
      #pragma unroll
      for (int m = 1; m < 4; ++m)
        v = fmaxf(v, fmaxf(fmaxf(s[qb][m][0], s[qb][m][1]),
                           fmaxf(s[qb][m][2], s[qb][m][3])));
      smax[qb] = v;
      viol = viol || (v > m_run[qb] + 11.0f);
    }
    if (__any(viol)) {
      float corrq[2];
      #pragma unroll
      for (int qb = 0; qb < 2; ++qb) {
        float v = smax[qb];
        v = fmaxf(v, __shfl_xor(v, 16, 64));
        v = fmaxf(v, __shfl_xor(v, 32, 64));
        const float mnew = fmaxf(m_run[qb], v);
        corrq[qb] = fexp2(m_run[qb] - mnew);
        m_run[qb] = mnew;
        l_par[qb] *= corrq[qb];
      }
      // oacc rows are q = 4*lg + r (+16qb): fetch corr from lane ln'=4lg+r
      #pragma unroll
      for (int qb = 0; qb < 2; ++qb)
        #pragma unroll
        for (int r = 0; r < 4; ++r) {
          const float c = __shfl(corrq[qb], 4 * lg + r, 64);
          #pragma unroll
          for (int df = 0; df < 4; ++df) oacc[qb][df][r] *= c;
        }
    }

    // ---- P = exp2(s - m), packed in-register into PV A-fragments ----
    bf16x8 pa[2][2];
    #pragma unroll
    for (int qb = 0; qb < 2; ++qb) {
      float pf[4][4];
      #pragma unroll
      for (int m = 0; m < 4; ++m)
        #pragma unroll
        for (int r = 0; r < 4; ++r) {
          const float p = fexp2(s[qb][m][r] - m_run[qb]);
          l_par[qb] += p;
          pf[m][r] = p;
        }
      #pragma unroll
      for (int kc = 0; kc < 2; ++kc) {
        union { u32 w[4]; bf16x8 v; } U;
        U.w[0] = pkbf(pf[2 * kc][0],     pf[2 * kc][1]);
        U.w[1] = pkbf(pf[2 * kc][2],     pf[2 * kc][3]);
        U.w[2] = pkbf(pf[2 * kc + 1][0], pf[2 * kc + 1][1]);
        U.w[3] = pkbf(pf[2 * kc + 1][2], pf[2 * kc + 1][3]);
        pa[qb][kc] = U.v;
      }
    }

    // ---- O += P @ V (V^T rows from LDS as B-operand) ----
    #pragma unroll
    for (int kc = 0; kc < 2; ++kc)
      #pragma unroll
      for (int df = 0; df < 4; ++df) {
        const int rv = 16 * df + ln;
        const int fz = (rv & 3) | (((rv >> 3) & 1) << 2);
        bf16x8 bv = *(const bf16x8*)&Vt_s[cur][rv][((kc * 4 + lg) ^ fz) * 8];
        oacc[0][df] = __builtin_amdgcn_mfma_f32_16x16x32_bf16(pa[0][kc], bv, oacc[0][df], 0, 0, 0);
        oacc[1][df] = __builtin_amdgcn_mfma_f32_16x16x32_bf16(pa[1][kc], bv, oacc[1][df], 0, 0, 0);
      }

    if (kt < 15) {
      *(uint4*)&K_s [cur ^ 1][srow][sw] = rk;
      *(uint4*)&Kf_s[cur ^ 1][srow][sw] = rf;
      *(uint4*)&Vt_s[cur ^ 1][srow][sw] = rv;
      __syncthreads();
      cur ^= 1;
    }
  }

  // epilogue: reduce l over the lg-group (lanes sharing q), write O + (m,l)
  #pragma unroll
  for (int qb = 0; qb < 2; ++qb) {
    l_par[qb] += __shfl_xor(l_par[qb], 16, 64);
    l_par[qb] += __shfl_xor(l_par[qb], 32, 64);
  }

  #pragma unroll
  for (int qb = 0; qb < 2; ++qb)
    #pragma unroll
    for (int df = 0; df < 4; ++df)
      #pragma unroll
      for (int r = 0; r < 4; ++r) {
        const int row = r0 + qb * 16 + 4 * lg + r;
        const int col = df * 16 + ln;
        Op[(size_t)row * 64 + col] = f2bf(oacc[qb][df][r]);
      }
  if (lane < 16) {                             // lg == 0
    #pragma unroll
    for (int qb = 0; qb < 2; ++qb) {
      const int grow = bh * 2048 + r0 + qb * 16 + ln;
      mlbuf[split * 32768 + grow] = make_float2(m_run[qb], l_par[qb]);
    }
  }
}

// ---------------------------------------------------------------------------
// Combine the two KV-split partials: out = sum_i O_i*a_i / sum_i l_i*a_i.
// grid 1024 x 256, 8 cols/thread. Coalesced row-major access.
// ---------------------------------------------------------------------------
__global__ __launch_bounds__(256) void combine(
    const u16* __restrict__ opart, const float2* __restrict__ mlbuf,
    u16* __restrict__ att) {
  const int gid = blockIdx.x * 256 + threadIdx.x;
  const int row = gid >> 3, c8 = (gid & 7) * 8;
  const float2 ml1 = mlbuf[row];
  const float2 ml2 = mlbuf[32768 + row];
  const float mx = fmaxf(ml1.x, ml2.x);
  const float a1 = fexp2(ml1.x - mx), a2 = fexp2(ml2.x - mx);
  const float inv = 1.0f / (ml1.y * a1 + ml2.y * a2);
  const float w1 = a1 * inv, w2 = a2 * inv;
  uint4 o1 = *(const uint4*)&opart[(size_t)row * 64 + c8];
  uint4 o2 = *(const uint4*)&opart[2097152 + (size_t)row * 64 + c8];
  const u16* p1 = (const u16*)&o1;
  const u16* p2 = (const u16*)&o2;
  alignas(16) u16 ot[8];
  #pragma unroll
  for (int i = 0; i < 8; ++i)
    ot[i] = cvbf(bf2f(p1[i]) * w1 + bf2f(p2[i]) * w2);
  *(uint4*)&att[(size_t)row * 64 + c8] = *(const uint4*)ot;
}

// ---------------------------------------------------------------------------
extern "C" void kernel_launch(void* const* d_in, const int* in_sizes, int n_in,
                              void* d_out, int out_size, void* d_ws, size_t ws_size,
                              hipStream_t stream) {
  const float* x    = (const float*)d_in[0];
  const float* xk   = (const float*)d_in[1];
  const float* Wv   = (const float*)d_in[2];  const float* bv   = (const float*)d_in[3];
  const float* Wk   = (const float*)d_in[4];  const float* bk   = (const float*)d_in[5];
  const float* Wq   = (const float*)d_in[6];  const float* bq   = (const float*)d_in[7];
  const float* Wkf  = (const float*)d_in[8];  const float* bkf  = (const float*)d_in[9];
  const float* Wqf  = (const float*)d_in[10]; const float* bqf  = (const float*)d_in[11];
  const float* Wq2  = (const float*)d_in[12]; const float* bq2  = (const float*)d_in[13];
  const float* Wk2  = (const float*)d_in[14]; const float* bk2  = (const float*)d_in[15];
  const float* Wqf2 = (const float*)d_in[16]; const float* bqf2 = (const float*)d_in[17];
  const float* Wkf2 = (const float*)d_in[18]; const float* bkf2 = (const float*)d_in[19];
  const float* Wo   = (const float*)d_in[20]; const float* bo   = (const float*)d_in[21];

  u16* ws = (u16*)d_ws;
  u16* Wt = ws;                                   // 10 x 262144 u16 (5120x512)
  float* biasP = (float*)(ws + 2621440);          // 5120 f32
  u16* bufs = ws + 2621440 + 10240;
  const size_t BUF = 2097152;
  u16* v1  = bufs + 0 * BUF;   // stage-1 v; later att (combine output)
  u16* k1  = bufs + 1 * BUF;   // (spare)
  u16* q1  = bufs + 2 * BUF;   // vt (V transposed per head)
  u16* kf1 = bufs + 3 * BUF;   // O_part split 0
  u16* qf1 = bufs + 4 * BUF;   // O_part split 1 (contiguous with kf1)
  u16* q2  = bufs + 5 * BUF;   // xb, then fused q2
  u16* k2  = bufs + 6 * BUF;   // xkb, then fused k2
  u16* qf2 = bufs + 7 * BUF;
  u16* kf2 = bufs + 8 * BUF;
  float2* mlbuf = (float2*)(bufs + 9 * BUF);      // 2 x 32768 float2
  u16* W1b = bufs + 9 * BUF + 262144;             // 4 x 262144 u16 (row-major bf16 W1)

  // 1. inputs -> bf16
  cvt_bf16<<<dim3(1024, 2), 256, 0, stream>>>(x, xk, q2, k2);

  // 2. W1 (Wq,Wk,Wqf,Wkf) -> bf16 row-major (wcomb B-operand)
  CPtrs cp;
  cp.p[0] = Wq; cp.p[1] = Wk; cp.p[2] = Wqf; cp.p[3] = Wkf;
  cvtW<<<dim3(128, 4), 256, 0, stream>>>(cp, W1b);

  // 3. weights -> bf16 transposed (slots 5,7 scaled); bias slots 0,9
  WPtrs wp;
  wp.w[0] = Wv;  wp.w[1] = Wk;  wp.w[2] = Wq;   wp.w[3] = Wkf;  wp.w[4] = Wqf;
  wp.w[5] = Wq2; wp.w[6] = Wk2; wp.w[7] = Wqf2; wp.w[8] = Wkf2; wp.w[9] = Wo;
  wp.b[0] = bv;  wp.b[1] = bk;  wp.b[2] = bq;   wp.b[3] = bkf;  wp.b[4] = bqf;
  wp.b[5] = bq2; wp.b[6] = bk2; wp.b[7] = bqf2; wp.b[8] = bkf2; wp.b[9] = bo;
  transposeW<<<dim3(8, 8, 10), 256, 0, stream>>>(wp, Wt, biasP);

  // 4. weight-combine: Weff^T = W2t(scaled) @ W1b^T  -> Wt slots 1..4
  //    z order: q,k,qf,kf  (A = slots 5,6,7,8)
  GemmBatch gw = {};
  gw.A[0] = Wt + 5 * 262144; gw.A[1] = Wt + 6 * 262144;
  gw.A[2] = Wt + 7 * 262144; gw.A[3] = Wt + 8 * 262144;
  gw.Ax = gw.A[0]; gw.xsplit = 100;
  gw.out[0] = Wt + 1 * 262144; gw.out[1] = Wt + 2 * 262144;
  gw.out[2] = Wt + 3 * 262144; gw.out[3] = Wt + 4 * 262144;
  gw.wrow0 = 0; gw.zstride = 512;
  gemm4<u16, true><<<dim3(4, 4, 4), 256, 0, stream>>>(gw, W1b, biasP);

  // 5. effective biases -> biasP rows 512..2559 (q,k,qf,kf)
  BEPtrs be;
  be.b1[0] = bq;  be.w2[0] = Wq2;  be.b2[0] = bq2;
  be.b1[1] = bk;  be.w2[1] = Wk2;  be.b2[1] = bk2;
  be.b1[2] = bqf; be.w2[2] = Wqf2; be.b2[2] = bqf2;
  be.b1[3] = bkf; be.w2[3] = Wkf2; be.b2[3] = bkf2;
  biasEff<<<dim3(4), 512, 0, stream>>>(be, biasP);

  // 6. mega stage-1: xb @ [Wv^T|Weff_q|Weff_k] -> v1,q2,k2 ;
  //                  xkb @ [Weff_qf|Weff_kf]   -> qf2,kf2
  GemmBatch g1 = {};
  g1.A[0] = q2;  g1.Ax = k2;  g1.xsplit = 12;
  g1.out[0] = v1; g1.out[1] = q2; g1.out[2] = k2; g1.out[3] = qf2; g1.out[4] = kf2;
  g1.wrow0 = 0; g1.zstride = 0;
  gemm4<u16, false><<<dim3(20, 32, 1), 256, 0, stream>>>(g1, Wt, biasP);

  // 7. V transpose per head-block (v1 -> q1)
  transposeV<<<dim3(32, 16), 256, 0, stream>>>(v1, q1);

  // 8. attention: 256 blocks x 512 threads (1/CU, 8 waves), KV-split x2
  attn8<<<dim3(256), 512, 0, stream>>>(q2, k2, qf2, kf2, q1, kf1, mlbuf);

  // 9. combine partials -> att (v1)
  combine<<<dim3(1024), 256, 0, stream>>>(kf1, mlbuf, v1);

  // 10. final: att @ Wo + bo -> d_out (fp32)
  GemmBatch g4 = {};
  g4.A[0] = v1; g4.Ax = v1; g4.xsplit = 100;
  g4.out[0] = d_out;
  g4.wrow0 = 4608; g4.zstride = 0;
  gemm4<float, false><<<dim3(4, 32, 1), 256, 0, stream>>>(g4, Wt, biasP);
}

// Round 17
// 103.650 us; speedup vs baseline: 1.1597x; 1.1597x over previous
//
#include <hip/hip_runtime.h>
#include <hip/hip_bf16.h>

typedef unsigned short u16;
typedef unsigned int   u32;
typedef __attribute__((ext_vector_type(8))) short bf16x8;
typedef __attribute__((ext_vector_type(4))) float f32x4;

#define SCALE 0.08838834764831845f                 // 1/sqrt(2*64)
#define SCLOG 0.12752040542575836f                 // SCALE * log2(e)

__device__ inline u16 f2bf(float f) {
  u32 u = __builtin_bit_cast(u32, f);
  u = (u + 0x7FFFu + ((u >> 16) & 1u)) >> 16;      // RNE
  return (u16)u;
}
__device__ inline float bf2f(u16 b) {
  u32 u = (u32)b << 16;
  return __builtin_bit_cast(float, u);
}
// HW bf16 cvt (compiler emits the HW cvt; scalar-cast path per m240)
__device__ __forceinline__ u16 cvbf(float f) {
  return __builtin_bit_cast(u16, __float2bfloat16(f));
}
__device__ __forceinline__ u32 pkbf(float a, float b) {   // low=a, high=b
  return (u32)cvbf(a) | ((u32)cvbf(b) << 16);
}
// raw v_exp_f32 (exp2): OCML exp2f is ~17 instr without fast-math
__device__ __forceinline__ float fexp2(float x) {
#if __has_builtin(__builtin_amdgcn_exp2f)
  return __builtin_amdgcn_exp2f(x);
#else
  float r; asm("v_exp_f32 %0, %1" : "=v"(r) : "v"(x)); return r;
#endif
}

// async global->LDS, 16B per lane; LDS dest is wave-uniform base + lane*16.
__device__ __forceinline__ void glds16(const u16* g, u16* l) {
  __builtin_amdgcn_global_load_lds(
      (__attribute__((address_space(1))) void*)g,
      (__attribute__((address_space(3))) void*)l, 16, 0, 0);
}

// ---------------------------------------------------------------------------
// fp32 -> bf16 bulk converts: x, xk (1024 blocks each) + 4 W1 weights
// (128 blocks each), one launch. grid (1024, 6), 8 elems/thr.
// ---------------------------------------------------------------------------
struct CvPtrs { const float* in[6]; u16* out[6]; int nblk[6]; };

__global__ __launch_bounds__(256) void cvtAll(CvPtrs cp) {
  const int y = blockIdx.y;
  if ((int)blockIdx.x >= cp.nblk[y]) return;
  const float* in = cp.in[y];
  u16* out = cp.out[y];
  const int i = (blockIdx.x * 256 + threadIdx.x) * 8;
  float4 f0 = *(const float4*)(in + i);
  float4 f1 = *(const float4*)(in + i + 4);
  alignas(16) u16 t[8] = {f2bf(f0.x), f2bf(f0.y), f2bf(f0.z), f2bf(f0.w),
                          f2bf(f1.x), f2bf(f1.y), f2bf(f1.z), f2bf(f1.w)};
  *(uint4*)(out + i) = *(const uint4*)t;
}

// ---------------------------------------------------------------------------
// Weight transpose Wt[z][n][k] = W[z][k][n] (fp32->bf16); slots 5,7 scaled
// by SCALE*log2e. Bias packed only for slots 0 (bv) and 9 (bo).
// ---------------------------------------------------------------------------
struct WPtrs { const float* w[10]; const float* b[10]; };

__global__ __launch_bounds__(256) void transposeW(WPtrs p, u16* __restrict__ out,
                                                  float* __restrict__ biasP) {
  __shared__ u16 ts[64][65];
  const int z = blockIdx.z;
  const float sc = (z == 5 || z == 7) ? SCLOG : 1.0f;
  const float* in = p.w[z];
  u16* o = out + (size_t)z * 262144;
  const int t = threadIdx.x;
  const int k0 = blockIdx.y * 64, n0 = blockIdx.x * 64;
  if (blockIdx.x == 0 && blockIdx.y == 0 && (z == 0 || z == 9)) {
    biasP[z * 512 + t]       = p.b[z][t];
    biasP[z * 512 + t + 256] = p.b[z][t + 256];
  }
  for (int pp = 0; pp < 16; ++pp) {
    int id = t + 256 * pp; int r = id >> 6, c = id & 63;
    ts[r][c] = f2bf(in[(size_t)(k0 + r) * 512 + n0 + c] * sc);
  }
  __syncthreads();
  for (int pp = 0; pp < 16; ++pp) {
    int id = t + 256 * pp; int r = id >> 6, c = id & 63;
    o[(size_t)(n0 + r) * 512 + k0 + c] = ts[c][r];
  }
}

// ---------------------------------------------------------------------------
// Effective bias (parallel): beff[n] = (b1 @ W2 + b2)[n] * sc.
// grid (4, 32) x 256 threads: 16 j-groups x 16 cols, LDS reduce.
// z order q,k,qf,kf -> biasP rows 512..2559.
// ---------------------------------------------------------------------------
struct BEPtrs { const float* b1[4]; const float* w2[4]; const float* b2[4]; };

__global__ __launch_bounds__(256) void biasEff(BEPtrs be, float* __restrict__ biasP) {
  __shared__ float red[16][17];
  const int z = blockIdx.x;
  const int n0 = blockIdx.y * 16;
  const float sc = (z == 0 || z == 2) ? SCLOG : 1.0f;
  const int nl = threadIdx.x & 15, jg = threadIdx.x >> 4;
  const float* b1 = be.b1[z];
  const float* w2 = be.w2[z];
  float s = 0.0f;
  #pragma unroll 4
  for (int jj = 0; jj < 32; ++jj) {
    const int j = jg * 32 + jj;
    s += b1[j] * w2[(size_t)j * 512 + n0 + nl];
  }
  red[jg][nl] = s;
  __syncthreads();
  if (threadIdx.x < 16) {
    float t = 0.0f;
    #pragma unroll
    for (int g = 0; g < 16; ++g) t += red[g][threadIdx.x];
    biasP[(1 + z) * 512 + n0 + threadIdx.x] =
        (t + be.b2[z][n0 + threadIdx.x]) * sc;
  }
}

// ---------------------------------------------------------------------------
// GEMM: 128x128 tile, BK=64, 4 waves (2x2) of 64x64. Single-buffered 32 KiB
// LDS with global_load_lds width-16 staging. Linear LDS. NB=true skips bias.
// ---------------------------------------------------------------------------
struct GemmBatch {
  const u16* A[4];
  const u16* Ax;
  int xsplit;
  void* out[5];        // indexed by (wrow>>9) - (wrow0>>9)
  int wrow0, zstride;
};

template <typename TOUT, bool NB>
__global__ __launch_bounds__(256, 4) void gemm4(GemmBatch gb,
    const u16* __restrict__ Wt, const float* __restrict__ biasP) {
  const int tx = blockIdx.x, z = blockIdx.z;
  const u16* A = (tx < gb.xsplit) ? gb.A[z] : gb.Ax;
  const int wrow = gb.wrow0 + z * gb.zstride + tx * 128;
  const int m0 = blockIdx.y * 128;
  const u16* B = Wt + (size_t)wrow * 512;
  const float* bias = biasP + wrow;

  const int t = threadIdx.x, wid = t >> 6, lane = t & 63;
  const int lg = lane >> 4, ln = lane & 15;
  const int wr = wid >> 1, wc = wid & 1;

  __shared__ u16 As[128][64];
  __shared__ u16 Bs[128][64];

  const u16* Ag = A + (size_t)m0 * 512;
  const int lrow = lane >> 3, lch = lane & 7;

  f32x4 acc[4][4];
  #pragma unroll
  for (int i = 0; i < 4; ++i)
    #pragma unroll
    for (int j = 0; j < 4; ++j)
      #pragma unroll
      for (int r = 0; r < 4; ++r) acc[i][j][r] = 0.0f;

  for (int kt = 0; kt < 8; ++kt) {
    #pragma unroll
    for (int c = 0; c < 4; ++c) {
      const int row = (wid * 4 + c) * 8 + lrow;
      const size_t go = (size_t)row * 512 + kt * 64 + lch * 8;
      glds16(Ag + go, &As[(wid * 4 + c) * 8][0]);
      glds16(B  + go, &Bs[(wid * 4 + c) * 8][0]);
    }
    __syncthreads();

    #pragma unroll
    for (int ck = 0; ck < 2; ++ck) {
      bf16x8 af[4], bfr[4];
      #pragma unroll
      for (int mi = 0; mi < 4; ++mi)
        af[mi] = *(const bf16x8*)&As[wr * 64 + mi * 16 + ln][ck * 32 + lg * 8];
      #pragma unroll
      for (int ni = 0; ni < 4; ++ni)
        bfr[ni] = *(const bf16x8*)&Bs[wc * 64 + ni * 16 + ln][ck * 32 + lg * 8];
      #pragma unroll
      for (int mi = 0; mi < 4; ++mi)
        #pragma unroll
        for (int ni = 0; ni < 4; ++ni)
          acc[mi][ni] = __builtin_amdgcn_mfma_f32_16x16x32_bf16(
              af[mi], bfr[ni], acc[mi][ni], 0, 0, 0);
    }
    if (kt < 7) __syncthreads();
  }

  TOUT* C = (TOUT*)gb.out[(wrow >> 9) - (gb.wrow0 >> 9)];
  const int nbase = wrow & 511;
  #pragma unroll
  for (int ni = 0; ni < 4; ++ni) {
    const int colw = wc * 64 + ni * 16 + ln;
    const float bv = NB ? 0.0f : bias[colw];
    const int col = nbase + colw;
    #pragma unroll
    for (int mi = 0; mi < 4; ++mi)
      #pragma unroll
      for (int r = 0; r < 4; ++r) {
        const int row = m0 + wr * 64 + mi * 16 + 4 * lg + r;
        const float val = acc[mi][ni][r] + bv;
        if constexpr (sizeof(TOUT) == 4) C[(size_t)row * 512 + col] = val;
        else                             C[(size_t)row * 512 + col] = f2bf(val);
      }
  }
}

// ---------------------------------------------------------------------------
// Per-head V transpose: v1 (2048,64) -> vt (64,2048) per head-block.
// grid (32,16).
// ---------------------------------------------------------------------------
__global__ __launch_bounds__(256) void transposeV(const u16* __restrict__ v1,
                                                  u16* __restrict__ vt) {
  __shared__ u16 ts[64][65];
  const size_t base = (size_t)blockIdx.y * 131072;
  const u16* in = v1 + base;
  u16* out = vt + base;
  const int l0 = blockIdx.x * 64;
  const int t = threadIdx.x;
  const int r = t >> 3, c8 = (t & 7) * 8;
  for (int pp = 0; pp < 2; ++pp) {
    int rr = r + pp * 32;
    *(uint4*)&ts[rr][c8] = *(const uint4*)&in[(size_t)(l0 + rr) * 64 + c8];
  }
  __syncthreads();
  for (int pp = 0; pp < 2; ++pp) {
    int d = r + pp * 32;
    alignas(16) u16 tmp[8];
    #pragma unroll
    for (int i = 0; i < 8; ++i) tmp[i] = ts[c8 + i][d];
    *(uint4*)&out[(size_t)d * 2048 + l0 + c8] = *(const uint4*)tmp;
  }
}

// ---------------------------------------------------------------------------
// Flash attention v8: swapped-operand S^T = mfma(K, Q) with permuted K-rows
// -> in-register P; lane-local defer-max; 8 waves x 32 q; KVBLK=64;
// KV-split x2; dbuf 48 KiB; grid 256 = 1 block/CU. fexp2 (raw v_exp_f32)
// and HW bf16 cvt. Q pre-scaled by SCALE*log2e (log2 domain).
// ---------------------------------------------------------------------------
__global__ __launch_bounds__(512) void attn8(
    const u16* __restrict__ q2, const u16* __restrict__ k2,
    const u16* __restrict__ qf2, const u16* __restrict__ kf2,
    const u16* __restrict__ vtg, u16* __restrict__ opart,
    float2* __restrict__ mlbuf) {
  const int id = blockIdx.x;
  const int nid = (id & 7) * 32 + (id >> 3);   // XCD-bijective
  const int split = nid & 1;
  const int qt = (nid >> 1) & 7;
  const int bh = nid >> 4;
  const size_t base = (size_t)bh * 131072;
  const int kv0 = split * 1024;

  const u16* Q  = q2  + base;
  const u16* Qf = qf2 + base;
  u16* Op = opart + (size_t)split * 2097152 + base;

  const int t = threadIdx.x, wid = t >> 6, lane = t & 63;
  const int lg = lane >> 4, ln = lane & 15;
  const int r0 = qt * 256 + wid * 32;          // this wave's 32 Q rows (local)

  __shared__ u16 K_s [2][64][64];
  __shared__ u16 Kf_s[2][64][64];
  __shared__ u16 Vt_s[2][64][64];

  const int srow = t >> 3, sch = t & 7;        // 64 rows x 8 chunks
  const int fsr = (srow & 3) | (((srow >> 3) & 1) << 2);
  const int sw = (sch ^ fsr) * 8;
  const u16* Ksrc  = k2  + base + (size_t)(kv0 + srow) * 64 + sch * 8;
  const u16* Kfsrc = kf2 + base + (size_t)(kv0 + srow) * 64 + sch * 8;
  const u16* Vsrc  = vtg + base + (size_t)srow * 2048 + kv0 + sch * 8;

  // Q fragments (B-operand: lane ln holds Q row r0+qb*16+ln, chunk lg)
  bf16x8 aq[2][4];
  #pragma unroll
  for (int qb = 0; qb < 2; ++qb) {
    const int row = r0 + qb * 16 + ln;
    aq[qb][0] = *(const bf16x8*)&Q [row * 64 +      lg * 8];
    aq[qb][1] = *(const bf16x8*)&Q [row * 64 + 32 + lg * 8];
    aq[qb][2] = *(const bf16x8*)&Qf[row * 64 +      lg * 8];
    aq[qb][3] = *(const bf16x8*)&Qf[row * 64 + 32 + lg * 8];
  }

  f32x4 oacc[2][4];
  #pragma unroll
  for (int qb = 0; qb < 2; ++qb)
    #pragma unroll
    for (int df = 0; df < 4; ++df)
      #pragma unroll
      for (int r = 0; r < 4; ++r) oacc[qb][df][r] = 0.0f;
  float m_run[2], l_par[2];
  #pragma unroll
  for (int qb = 0; qb < 2; ++qb) { m_run[qb] = -1e30f; l_par[qb] = 0.0f; }

  // A-operand K-row permutation: kv(m,r,lg) = 32*(m>>1)+8*lg+4*(m&1)+r
  const int rbase = 8 * (ln >> 2) + (ln & 3);

  // prologue: stage tile 0
  uint4 rk = *(const uint4*)(Ksrc);
  uint4 rf = *(const uint4*)(Kfsrc);
  uint4 rv = *(const uint4*)(Vsrc);
  *(uint4*)&K_s [0][srow][sw] = rk;
  *(uint4*)&Kf_s[0][srow][sw] = rf;
  *(uint4*)&Vt_s[0][srow][sw] = rv;
  __syncthreads();

  int cur = 0;
  for (int kt = 0; kt < 16; ++kt) {
    if (kt < 15) {                             // issue next-tile loads early
      const int ko = (kt + 1) * 4096;
      rk = *(const uint4*)(Ksrc  + ko);
      rf = *(const uint4*)(Kfsrc + ko);
      rv = *(const uint4*)(Vsrc  + (kt + 1) * 64);
    }

    // ---- S^T = K Q^T + Kf Qf^T : s[qb][m][r] = S[q=r0+16qb+ln][kv(m,r,lg)]
    f32x4 s[2][4];
    #pragma unroll
    for (int m = 0; m < 4; ++m) {
      const int rowg = rbase + 4 * (m & 1) + 32 * (m >> 1);
      const int fz = (rowg & 3) | (((rowg >> 3) & 1) << 2);
      bf16x8 a0 = *(const bf16x8*)&K_s [cur][rowg][((0 + lg) ^ fz) * 8];
      bf16x8 a1 = *(const bf16x8*)&K_s [cur][rowg][((4 + lg) ^ fz) * 8];
      bf16x8 a2 = *(const bf16x8*)&Kf_s[cur][rowg][((0 + lg) ^ fz) * 8];
      bf16x8 a3 = *(const bf16x8*)&Kf_s[cur][rowg][((4 + lg) ^ fz) * 8];
      #pragma unroll
      for (int qb = 0; qb < 2; ++qb) {
        f32x4 a;
        #pragma unroll
        for (int r = 0; r < 4; ++r) a[r] = 0.0f;
        a = __builtin_amdgcn_mfma_f32_16x16x32_bf16(a0, aq[qb][0], a, 0, 0, 0);
        a = __builtin_amdgcn_mfma_f32_16x16x32_bf16(a1, aq[qb][1], a, 0, 0, 0);
        a = __builtin_amdgcn_mfma_f32_16x16x32_bf16(a2, aq[qb][2], a, 0, 0, 0);
        a = __builtin_amdgcn_mfma_f32_16x16x32_bf16(a3, aq[qb][3], a, 0, 0, 0);
        s[qb][m] = a;
      }
    }

    // ---- lane-local defer-max softmax (q = ln + 16*qb per lane) ----
    float smax[2];
    bool viol = false;
    #pragma unroll
    for (int qb = 0; qb < 2; ++qb) {
      float v = fmaxf(fmaxf(s[qb][0][0], s[qb][0][1]),
                      fmaxf(s[qb][0][2], s[qb][0][3]));
      #pragma unroll
      for (int m = 1; m < 4; ++m)
        v = fmaxf(v, fmaxf(fmaxf(s[qb][m][0], s[qb][m][1]),
                           fmaxf(s[qb][m][2], s[qb][m][3])));
      smax[qb] = v;
      viol = viol || (v > m_run[qb] + 11.0f);
    }
    if (__any(viol)) {
      float corrq[2];
      #pragma unroll
      for (int qb = 0; qb < 2; ++qb) {
        float v = smax[qb];
        v = fmaxf(v, __shfl_xor(v, 16, 64));
        v = fmaxf(v, __shfl_xor(v, 32, 64));
        const float mnew = fmaxf(m_run[qb], v);
        corrq[qb] = fexp2(m_run[qb] - mnew);
        m_run[qb] = mnew;
        l_par[qb] *= corrq[qb];
      }
      // oacc rows are q = 4*lg + r (+16qb): fetch corr from lane ln'=4lg+r
      #pragma unroll
      for (int qb = 0; qb < 2; ++qb)
        #pragma unroll
        for (int r = 0; r < 4; ++r) {
          const float c = __shfl(corrq[qb], 4 * lg + r, 64);
          #pragma unroll
          for (int df = 0; df < 4; ++df) oacc[qb][df][r] *= c;
        }
    }

    // ---- P = exp2(s - m), packed in-register into PV A-fragments ----
    bf16x8 pa[2][2];
    #pragma unroll
    for (int qb = 0; qb < 2; ++qb) {
      float pf[4][4];
      #pragma unroll
      for (int m = 0; m < 4; ++m)
        #pragma unroll
        for (int r = 0; r < 4; ++r) {
          const float p = fexp2(s[qb][m][r] - m_run[qb]);
          l_par[qb] += p;
          pf[m][r] = p;
        }
      #pragma unroll
      for (int kc = 0; kc < 2; ++kc) {
        union { u32 w[4]; bf16x8 v; } U;
        U.w[0] = pkbf(pf[2 * kc][0],     pf[2 * kc][1]);
        U.w[1] = pkbf(pf[2 * kc][2],     pf[2 * kc][3]);
        U.w[2] = pkbf(pf[2 * kc + 1][0], pf[2 * kc + 1][1]);
        U.w[3] = pkbf(pf[2 * kc + 1][2], pf[2 * kc + 1][3]);
        pa[qb][kc] = U.v;
      }
    }

    // ---- O += P @ V (V^T rows from LDS as B-operand) ----
    #pragma unroll
    for (int kc = 0; kc < 2; ++kc)
      #pragma unroll
      for (int df = 0; df < 4; ++df) {
        const int rv = 16 * df + ln;
        const int fz = (rv & 3) | (((rv >> 3) & 1) << 2);
        bf16x8 bv = *(const bf16x8*)&Vt_s[cur][rv][((kc * 4 + lg) ^ fz) * 8];
        oacc[0][df] = __builtin_amdgcn_mfma_f32_16x16x32_bf16(pa[0][kc], bv, oacc[0][df], 0, 0, 0);
        oacc[1][df] = __builtin_amdgcn_mfma_f32_16x16x32_bf16(pa[1][kc], bv, oacc[1][df], 0, 0, 0);
      }

    if (kt < 15) {
      *(uint4*)&K_s [cur ^ 1][srow][sw] = rk;
      *(uint4*)&Kf_s[cur ^ 1][srow][sw] = rf;
      *(uint4*)&Vt_s[cur ^ 1][srow][sw] = rv;
      __syncthreads();
      cur ^= 1;
    }
  }

  // epilogue: reduce l over the lg-group (lanes sharing q), write O + (m,l)
  #pragma unroll
  for (int qb = 0; qb < 2; ++qb) {
    l_par[qb] += __shfl_xor(l_par[qb], 16, 64);
    l_par[qb] += __shfl_xor(l_par[qb], 32, 64);
  }

  #pragma unroll
  for (int qb = 0; qb < 2; ++qb)
    #pragma unroll
    for (int df = 0; df < 4; ++df)
      #pragma unroll
      for (int r = 0; r < 4; ++r) {
        const int row = r0 + qb * 16 + 4 * lg + r;
        const int col = df * 16 + ln;
        Op[(size_t)row * 64 + col] = f2bf(oacc[qb][df][r]);
      }
  if (lane < 16) {                             // lg == 0
    #pragma unroll
    for (int qb = 0; qb < 2; ++qb) {
      const int grow = bh * 2048 + r0 + qb * 16 + ln;
      mlbuf[split * 32768 + grow] = make_float2(m_run[qb], l_par[qb]);
    }
  }
}

// ---------------------------------------------------------------------------
// Combine the two KV-split partials: out = sum_i O_i*a_i / sum_i l_i*a_i.
// grid 1024 x 256, 8 cols/thread. Coalesced row-major access.
// ---------------------------------------------------------------------------
__global__ __launch_bounds__(256) void combine(
    const u16* __restrict__ opart, const float2* __restrict__ mlbuf,
    u16* __restrict__ att) {
  const int gid = blockIdx.x * 256 + threadIdx.x;
  const int row = gid >> 3, c8 = (gid & 7) * 8;
  const float2 ml1 = mlbuf[row];
  const float2 ml2 = mlbuf[32768 + row];
  const float mx = fmaxf(ml1.x, ml2.x);
  const float a1 = fexp2(ml1.x - mx), a2 = fexp2(ml2.x - mx);
  const float inv = 1.0f / (ml1.y * a1 + ml2.y * a2);
  const float w1 = a1 * inv, w2 = a2 * inv;
  uint4 o1 = *(const uint4*)&opart[(size_t)row * 64 + c8];
  uint4 o2 = *(const uint4*)&opart[2097152 + (size_t)row * 64 + c8];
  const u16* p1 = (const u16*)&o1;
  const u16* p2 = (const u16*)&o2;
  alignas(16) u16 ot[8];
  #pragma unroll
  for (int i = 0; i < 8; ++i)
    ot[i] = cvbf(bf2f(p1[i]) * w1 + bf2f(p2[i]) * w2);
  *(uint4*)&att[(size_t)row * 64 + c8] = *(const uint4*)ot;
}

// ---------------------------------------------------------------------------
extern "C" void kernel_launch(void* const* d_in, const int* in_sizes, int n_in,
                              void* d_out, int out_size, void* d_ws, size_t ws_size,
                              hipStream_t stream) {
  const float* x    = (const float*)d_in[0];
  const float* xk   = (const float*)d_in[1];
  const float* Wv   = (const float*)d_in[2];  const float* bv   = (const float*)d_in[3];
  const float* Wk   = (const float*)d_in[4];  const float* bk   = (const float*)d_in[5];
  const float* Wq   = (const float*)d_in[6];  const float* bq   = (const float*)d_in[7];
  const float* Wkf  = (const float*)d_in[8];  const float* bkf  = (const float*)d_in[9];
  const float* Wqf  = (const float*)d_in[10]; const float* bqf  = (const float*)d_in[11];
  const float* Wq2  = (const float*)d_in[12]; const float* bq2  = (const float*)d_in[13];
  const float* Wk2  = (const float*)d_in[14]; const float* bk2  = (const float*)d_in[15];
  const float* Wqf2 = (const float*)d_in[16]; const float* bqf2 = (const float*)d_in[17];
  const float* Wkf2 = (const float*)d_in[18]; const float* bkf2 = (const float*)d_in[19];
  const float* Wo   = (const float*)d_in[20]; const float* bo   = (const float*)d_in[21];

  u16* ws = (u16*)d_ws;
  u16* Wt = ws;                                   // 10 x 262144 u16 (5120x512)
  float* biasP = (float*)(ws + 2621440);          // 5120 f32
  u16* bufs = ws + 2621440 + 10240;
  const size_t BUF = 2097152;
  u16* b0 = bufs + 0 * BUF;    // v1 (stage-1), later att (combine out)
  u16* b1 = bufs + 1 * BUF;    // q2 (fused)
  u16* b2 = bufs + 2 * BUF;    // vt
  u16* b3 = bufs + 3 * BUF;    // k2 (fused)
  u16* b5 = bufs + 5 * BUF;    // xb; later O_part split 0
  u16* b6 = bufs + 6 * BUF;    // xkb; later O_part split 1 (contig with b5)
  u16* b7 = bufs + 7 * BUF;    // qf2 (fused)
  u16* b8 = bufs + 8 * BUF;    // kf2 (fused)
  float2* mlbuf = (float2*)(bufs + 9 * BUF);      // 2 x 32768 float2 (512 KB)
  u16* W1b = bufs + 9 * BUF + 262144;             // 4 x 262144 u16 (row-major W1)

  // 1. all fp32->bf16 converts in one launch: x->b5, xk->b6, W1 x4 -> W1b
  CvPtrs cp;
  cp.in[0] = x;   cp.out[0] = b5;             cp.nblk[0] = 1024;
  cp.in[1] = xk;  cp.out[1] = b6;             cp.nblk[1] = 1024;
  cp.in[2] = Wq;  cp.out[2] = W1b;            cp.nblk[2] = 128;
  cp.in[3] = Wk;  cp.out[3] = W1b + 262144;   cp.nblk[3] = 128;
  cp.in[4] = Wqf; cp.out[4] = W1b + 524288;   cp.nblk[4] = 128;
  cp.in[5] = Wkf; cp.out[5] = W1b + 786432;   cp.nblk[5] = 128;
  cvtAll<<<dim3(1024, 6), 256, 0, stream>>>(cp);

  // 2. weights -> bf16 transposed (slots 5,7 scaled); bias slots 0,9
  WPtrs wp;
  wp.w[0] = Wv;  wp.w[1] = Wk;  wp.w[2] = Wq;   wp.w[3] = Wkf;  wp.w[4] = Wqf;
  wp.w[5] = Wq2; wp.w[6] = Wk2; wp.w[7] = Wqf2; wp.w[8] = Wkf2; wp.w[9] = Wo;
  wp.b[0] = bv;  wp.b[1] = bk;  wp.b[2] = bq;   wp.b[3] = bkf;  wp.b[4] = bqf;
  wp.b[5] = bq2; wp.b[6] = bk2; wp.b[7] = bqf2; wp.b[8] = bkf2; wp.b[9] = bo;
  transposeW<<<dim3(8, 8, 10), 256, 0, stream>>>(wp, Wt, biasP);

  // 3. weight-combine: Weff^T = W2t(scaled) @ W1b^T -> Wt slots 1..4
  //    z order: q,k,qf,kf (A = slots 5,6,7,8)
  GemmBatch gw = {};
  gw.A[0] = Wt + 5 * 262144; gw.A[1] = Wt + 6 * 262144;
  gw.A[2] = Wt + 7 * 262144; gw.A[3] = Wt + 8 * 262144;
  gw.Ax = gw.A[0]; gw.xsplit = 100;
  gw.out[0] = Wt + 1 * 262144; gw.out[1] = Wt + 2 * 262144;
  gw.out[2] = Wt + 3 * 262144; gw.out[3] = Wt + 4 * 262144;
  gw.wrow0 = 0; gw.zstride = 512;
  gemm4<u16, true><<<dim3(4, 4, 4), 256, 0, stream>>>(gw, W1b, biasP);

  // 4. effective biases -> biasP rows 512..2559 (q,k,qf,kf), parallel
  BEPtrs be;
  be.b1[0] = bq;  be.w2[0] = Wq2;  be.b2[0] = bq2;
  be.b1[1] = bk;  be.w2[1] = Wk2;  be.b2[1] = bk2;
  be.b1[2] = bqf; be.w2[2] = Wqf2; be.b2[2] = bqf2;
  be.b1[3] = bkf; be.w2[3] = Wkf2; be.b2[3] = bkf2;
  biasEff<<<dim3(4, 32), 256, 0, stream>>>(be, biasP);

  // 5. mega stage-1 (no aliasing): xb @ [Wv^T|Weff_q|Weff_k] -> b0,b1,b3 ;
  //                                xkb @ [Weff_qf|Weff_kf]   -> b7,b8
  GemmBatch g1 = {};
  g1.A[0] = b5;  g1.Ax = b6;  g1.xsplit = 12;
  g1.out[0] = b0; g1.out[1] = b1; g1.out[2] = b3; g1.out[3] = b7; g1.out[4] = b8;
  g1.wrow0 = 0; g1.zstride = 0;
  gemm4<u16, false><<<dim3(20, 32, 1), 256, 0, stream>>>(g1, Wt, biasP);

  // 6. V transpose per head-block (b0 -> b2)
  transposeV<<<dim3(32, 16), 256, 0, stream>>>(b0, b2);

  // 7. attention: 256 blocks x 512 threads (1/CU, 8 waves), KV-split x2
  //    O_part -> b5|b6 (xb/xkb dead)
  attn8<<<dim3(256), 512, 0, stream>>>(b1, b3, b7, b8, b2, b5, mlbuf);

  // 8. combine partials -> att (b0)
  combine<<<dim3(1024), 256, 0, stream>>>(b5, mlbuf, b0);

  // 9. final: att @ Wo + bo -> d_out (fp32)
  GemmBatch g4 = {};
  g4.A[0] = b0; g4.Ax = b0; g4.xsplit = 100;
  g4.out[0] = d_out;
  g4.wrow0 = 4608; g4.zstride = 0;
  gemm4<float, false><<<dim3(4, 32, 1), 256, 0, stream>>>(g4, Wt, biasP);
}